// Round 4
// baseline (299.751 us; speedup 1.0000x reference)
//
#include <hip/hip_runtime.h>
#include <hip/hip_bf16.h>
#include <stdint.h>

#define B_ROWS 4096
#define L_FEAT 256
#define VOCAB  8192

#define BM 128
#define BN 128
#define BK 64            // int8 MFMA K
#define NSTEP (VOCAB / BK)   // 128

typedef __attribute__((ext_vector_type(4))) int   intx4;
typedef __attribute__((ext_vector_type(4))) float floatx4;

__device__ __forceinline__ void async_copy16(const void* gsrc, void* ldst) {
  __builtin_amdgcn_global_load_lds(
      (const __attribute__((address_space(1))) void*)gsrc,
      (__attribute__((address_space(3))) void*)ldst, 16, 0, 0);
}

// ---------------- kernel 1: fused zero+scatter+sizes -------------------------
__global__ __launch_bounds__(256) void presence_kernel(
    const int* __restrict__ f,
    unsigned char* __restrict__ P,
    float* __restrict__ sizes) {
  __shared__ __align__(16) unsigned char row_p[VOCAB];  // 8 KB
  const int row = blockIdx.x;
  const int tid = threadIdx.x;

  uint4* rp4 = (uint4*)row_p;
  const uint4 z = make_uint4(0u, 0u, 0u, 0u);
  #pragma unroll
  for (int j = 0; j < 2; ++j) rp4[tid + j * 256] = z;   // 512 uint4 = 8 KB
  __syncthreads();

  const int v = f[row * L_FEAT + tid];  // one feature per thread
  row_p[v] = 1;                         // duplicates benign
  __syncthreads();

  int cnt = 0;
  uint4* op4 = (uint4*)(P + (size_t)row * VOCAB);
  #pragma unroll
  for (int j = 0; j < 2; ++j) {
    const uint4 x = rp4[tid + j * 256];
    op4[tid + j * 256] = x;
    cnt += __popc(x.x) + __popc(x.y) + __popc(x.z) + __popc(x.w);
  }
  #pragma unroll
  for (int off = 32; off > 0; off >>= 1) cnt += __shfl_down(cnt, off);
  __shared__ int ws[4];
  if ((tid & 63) == 0) ws[tid >> 6] = cnt;
  __syncthreads();
  if (tid == 0) sizes[row] = (float)(ws[0] + ws[1] + ws[2] + ws[3]);
}

// ---------------- kernel 2: inter = P·P^T (i8 MFMA) + Jaccard + mirror -------
// Round-4: LDS-BW was the binding pipe (513 cyc/block-step ≈ measured 1084/2).
//   * B-fragments now load DIRECTLY global->VGPR (L2-resident panel), bypassing
//     LDS entirely for B: LDS traffic halves -> MFMA pipe becomes binding.
//   * A stays LDS-staged: 4 buffers (32 KB), depth-3 prefetch.
//   * register dbuf: a-frags ds_read 1 step ahead; b-frags global-loaded 2
//     steps ahead. Every iter issues exactly {2 stage + 4 bload}; the loop-top
//     `s_waitcnt vmcnt(6)` keeps exactly one iteration's loads in flight
//     across the barrier (stage(i+1) landed for ds_read, bload(i) landed for
//     MFMA). Never drains to 0.
//   * manual 2x unroll so all frag arrays are statically indexed (no scratch).
//   * sched_barrier(0) after s_barrier: ds_reads must not hoist above the
//     cross-wave staging-complete point.
__global__ __launch_bounds__(256, 2) void gemm_kernel(
    const unsigned char* __restrict__ P,
    const float* __restrict__ sizes,
    float* __restrict__ out) {
  // XCD swizzle (528 = 8*66 -> bijective) then triangle decode, bx >= by
  int bid = blockIdx.x;
  bid = (bid & 7) * 66 + (bid >> 3);
  int b = bid, by = 0, rem = 32;
  while (b >= rem) { b -= rem; ++by; --rem; }
  const int bx = by + b;
  const int iBase = by * BM;   // output rows
  const int jBase = bx * BN;   // output cols

  __shared__ __align__(16) unsigned char As[4][BM * BK];  // 4 x 8 KB = 32 KB

  const int tid  = threadIdx.x;
  const int wave = tid >> 6, lane = tid & 63;
  const int wm = wave >> 1, wn = wave & 1;   // 2x2 wave grid, each wave 64x64
  const int col16 = lane & 15, quad = lane >> 4;

  intx4 acc[4][4];
  #pragma unroll
  for (int ai = 0; ai < 4; ++ai)
    #pragma unroll
    for (int ci = 0; ci < 4; ++ci) acc[ai][ci] = (intx4){0, 0, 0, 0};

  // A staging geometry: chunk = 16 rows x 64 cols = 1 KB; lane l -> row l>>2,
  // LDS slot (l&3), dst = chunk_base + lane*16 (linear, wave-uniform base).
  // Source chunk PRE-SWIZZLED (involution) so the ds_read side XOR-swizzles.
  const int srow = lane >> 2;                          // 0..15 within chunk
  const int scol = ((lane & 3) ^ ((lane >> 3) & 3)) * 16;
  const int sw   = (col16 >> 1) & 3;  // read-side swizzle == (row>>1)&3

  #define STAGE_A(buf, k0)                                                    \
    {                                                                         \
      _Pragma("unroll")                                                       \
      for (int t = 0; t < 2; ++t) {                                           \
        const int c = wave + t * 4;       /* chunk 0..7 */                    \
        const int r = c * 16 + srow;      /* tile row 0..127 */               \
        async_copy16(P + (size_t)(iBase + r) * VOCAB + (k0) + scol,           \
                     &As[buf][c * 1024]);                                     \
      }                                                                       \
    }

  // B row base pointers (per lane): row jBase + wn*64 + tn*16 + col16,
  // byte offset quad*16 within the 64-byte K-slice.
  const unsigned char* pB0 =
      P + (size_t)(jBase + wn * 64 + 0 * 16 + col16) * VOCAB + quad * 16;
  const unsigned char* pB1 = pB0 + (size_t)16 * VOCAB;
  const unsigned char* pB2 = pB0 + (size_t)32 * VOCAB;
  const unsigned char* pB3 = pB0 + (size_t)48 * VOCAB;

  #define BLOAD(breg, k0)                                                     \
    {                                                                         \
      breg[0] = *(const intx4*)(pB0 + (k0));                                  \
      breg[1] = *(const intx4*)(pB1 + (k0));                                  \
      breg[2] = *(const intx4*)(pB2 + (k0));                                  \
      breg[3] = *(const intx4*)(pB3 + (k0));                                  \
    }

  #define DSA(areg, buf)                                                      \
    {                                                                         \
      _Pragma("unroll")                                                       \
      for (int tm = 0; tm < 4; ++tm)                                          \
        areg[tm] = *(const intx4*)&As[buf][(wm * 64 + tm * 16 + col16) * BK + \
                                           ((quad ^ sw) * 16)];               \
    }

  #define MFMA16(areg, breg)                                                  \
    {                                                                         \
      __builtin_amdgcn_s_setprio(1);                                          \
      _Pragma("unroll")                                                       \
      for (int tm = 0; tm < 4; ++tm)                                          \
        _Pragma("unroll")                                                     \
        for (int tn = 0; tn < 4; ++tn)                                        \
          acc[tm][tn] = __builtin_amdgcn_mfma_i32_16x16x64_i8(                \
              areg[tm], breg[tn], acc[tm][tn], 0, 0, 0);                      \
      __builtin_amdgcn_s_setprio(0);                                          \
    }

  intx4 a0[4], a1[4], b0[4], b1[4];

  // prologue — issue order matters for the positional vmcnt counts:
  // S0(2) B0(4) S1(2) B1(4) S2(2) = 14 vm-ops
  STAGE_A(0, 0);
  BLOAD(b0, 0);
  STAGE_A(1, BK);
  BLOAD(b1, BK);
  STAGE_A(2, 2 * BK);
  asm volatile("s_waitcnt vmcnt(12)" ::: "memory");  // S0 landed (this wave)
  __builtin_amdgcn_s_barrier();                      // all waves' S0 landed
  __builtin_amdgcn_sched_barrier(0);
  DSA(a0, 0);

  // steady state: each iter issues S(i+3)[2] + B(i+2)[4]; at loop top,
  // vmcnt(6) leaves exactly {S(i+2), B(i+1)} in flight -> S(i+1) landed
  // (ds_read safe after barrier) and B(i) landed (MFMA operands ready).
  for (int ii = 0; ii < NSTEP / 2; ++ii) {
    {
      const int i = 2 * ii;
      asm volatile("s_waitcnt vmcnt(6)" ::: "memory");
      __builtin_amdgcn_s_barrier();
      __builtin_amdgcn_sched_barrier(0);
      DSA(a1, (i + 1) & 3);                         // prefetch a(i+1)
      STAGE_A((i + 3) & 3, ((i + 3) * BK) & (VOCAB - 1));
      MFMA16(a0, b0);
      BLOAD(b0, ((i + 2) * BK) & (VOCAB - 1));      // b(i+2), reuse parity-0
    }
    {
      const int i = 2 * ii + 1;
      asm volatile("s_waitcnt vmcnt(6)" ::: "memory");
      __builtin_amdgcn_s_barrier();
      __builtin_amdgcn_sched_barrier(0);
      DSA(a0, (i + 1) & 3);                         // prefetch a(i+1)
      STAGE_A((i + 3) & 3, ((i + 3) * BK) & (VOCAB - 1));
      MFMA16(a1, b1);
      BLOAD(b1, ((i + 2) * BK) & (VOCAB - 1));      // b(i+2), parity-1
    }
  }

  // epilogue: sim = -inter / (|A_i| + |A_j| - inter); write value + mirror.
  // nontemporal: out is write-only -> don't evict P from L2/L3.
  #pragma unroll
  for (int tm = 0; tm < 4; ++tm) {
    const int rowb = iBase + wm * 64 + tm * 16 + quad * 4;
    const float si0 = sizes[rowb + 0], si1 = sizes[rowb + 1];
    const float si2 = sizes[rowb + 2], si3 = sizes[rowb + 3];
    #pragma unroll
    for (int tn = 0; tn < 4; ++tn) {
      const int col = jBase + wn * 64 + tn * 16 + col16;
      const float sj = sizes[col];
      floatx4 tv;
      {
        const float inter = (float)acc[tm][tn][0];
        const float u = si0 + sj - inter;
        tv[0] = (u != 0.f) ? (-inter / u) : 0.f;
      }
      {
        const float inter = (float)acc[tm][tn][1];
        const float u = si1 + sj - inter;
        tv[1] = (u != 0.f) ? (-inter / u) : 0.f;
      }
      {
        const float inter = (float)acc[tm][tn][2];
        const float u = si2 + sj - inter;
        tv[2] = (u != 0.f) ? (-inter / u) : 0.f;
      }
      {
        const float inter = (float)acc[tm][tn][3];
        const float u = si3 + sj - inter;
        tv[3] = (u != 0.f) ? (-inter / u) : 0.f;
      }
      // upper-triangle tile element (row-major, 4 scalar rows at fixed col)
      __builtin_nontemporal_store(tv[0], &out[(size_t)(rowb + 0) * B_ROWS + col]);
      __builtin_nontemporal_store(tv[1], &out[(size_t)(rowb + 1) * B_ROWS + col]);
      __builtin_nontemporal_store(tv[2], &out[(size_t)(rowb + 2) * B_ROWS + col]);
      __builtin_nontemporal_store(tv[3], &out[(size_t)(rowb + 3) * B_ROWS + col]);
      // mirrored element: 4 row-values are contiguous in the transposed row
      __builtin_nontemporal_store(tv, (floatx4*)&out[(size_t)col * B_ROWS + rowb]);
    }
  }
}

// ---------------- launcher ---------------------------------------------------
extern "C" void kernel_launch(void* const* d_in, const int* in_sizes, int n_in,
                              void* d_out, int out_size, void* d_ws, size_t ws_size,
                              hipStream_t stream) {
  const int* features = (const int*)d_in[0];
  float* out = (float*)d_out;
  unsigned char* P = (unsigned char*)d_ws;                        // 32 MB int8
  float* sizes = (float*)((char*)d_ws + (size_t)B_ROWS * VOCAB);  // +16 KB

  presence_kernel<<<B_ROWS, 256, 0, stream>>>(features, P, sizes);
  gemm_kernel<<<528, 256, 0, stream>>>(P, sizes, out);
}

// Round 5
// 248.767 us; speedup vs baseline: 1.2049x; 1.2049x over previous
//
#include <hip/hip_runtime.h>
#include <stdint.h>

#define B_ROWS 4096
#define L_FEAT 256
#define VOCAB  8192
#define ROWB   (VOCAB / 2)      // 4096 bytes per row in fp4 (2 elems/byte)
#define BM 128
#define BN 128
#define BKE 64                  // K elements per step (one 32x32x64 MFMA)
#define BKB 32                  // K bytes per step
#define NSTEP (VOCAB / BKE)     // 128

typedef __attribute__((ext_vector_type(4)))  int   intx4;
typedef __attribute__((ext_vector_type(8)))  int   intx8;
typedef __attribute__((ext_vector_type(4)))  float floatx4;
typedef __attribute__((ext_vector_type(16))) float floatx16;

__device__ __forceinline__ void async_copy16(const void* gsrc, void* ldst) {
  __builtin_amdgcn_global_load_lds(
      (const __attribute__((address_space(1))) void*)gsrc,
      (__attribute__((address_space(3))) void*)ldst, 16, 0, 0);
}

// ---------------- kernel 1: fused zero+scatter+sizes (fp4 presence) ----------
// One block per row: build the 4KB fp4 presence row in LDS, write coalesced,
// popcount for row size. fp4 e2m1: nibble 0x2 == 1.0. Two values share a byte,
// so scatter uses LDS atomicOr on 32-bit words (8 nibbles/word).
__global__ __launch_bounds__(256) void presence_kernel(
    const int* __restrict__ f,
    uint32_t* __restrict__ P,     // fp4 presence, ROWB bytes per row
    float* __restrict__ sizes) {
  __shared__ uint32_t rw[VOCAB / 8];   // 1024 words = 4 KB
  const int row = blockIdx.x;
  const int tid = threadIdx.x;

  #pragma unroll
  for (int j = 0; j < 4; ++j) rw[tid + j * 256] = 0u;
  __syncthreads();

  const int v = f[row * L_FEAT + tid];            // one feature per thread
  atomicOr(&rw[v >> 3], 0x2u << ((v & 7) * 4));   // nibble = 1.0 (dups benign)
  __syncthreads();

  // 256 uint4 = 4 KB: exactly one per thread
  const uint4 x = ((const uint4*)rw)[tid];
  ((uint4*)(P + (size_t)row * (ROWB / 4)))[tid] = x;
  int cnt = __popc(x.x & 0x22222222u) + __popc(x.y & 0x22222222u) +
            __popc(x.z & 0x22222222u) + __popc(x.w & 0x22222222u);
  #pragma unroll
  for (int off = 32; off > 0; off >>= 1) cnt += __shfl_down(cnt, off);
  __shared__ int ws[4];
  if ((tid & 63) == 0) ws[tid >> 6] = cnt;
  __syncthreads();
  if (tid == 0) sizes[row] = (float)(ws[0] + ws[1] + ws[2] + ws[3]);
}

// ---------------- kernel 2: inter = P·P^T (fp4 MX MFMA) + Jaccard + mirror ---
// 128x128 tile, 4 waves 2x2, each wave 64x64 via 2x2 mfma_scale_f32_32x32x64
// (fp4 A/B, unit e8m0 scales). K-step = 64 elems = 32 B/row.
// Fragment-linear LDS: A-operand layout is row=lane&31, khalf=lane>>5, so each
// 32-row fragment is staged with per-lane source = exactly that lane's 16 B;
// global_load_lds writes base+lane*16 and ds_read reads base+lane*16 -> fully
// sequential, conflict-free, no swizzle. Round-3 proven pipeline skeleton:
// 3 buffers (24 KB), depth-2 prefetch, loop-top counted vmcnt(2) (never 0),
// one s_barrier per K-step, setprio around MFMA, XCD swizzle, nt stores,
// fused mirror epilogue.
__global__ __launch_bounds__(256) void gemm_kernel(
    const unsigned char* __restrict__ P,
    const float* __restrict__ sizes,
    float* __restrict__ out) {
  // XCD swizzle (528 = 8*66 -> bijective) then triangle decode, bx >= by
  int bid = blockIdx.x;
  bid = (bid & 7) * 66 + (bid >> 3);
  int b = bid, by = 0, rem = 32;
  while (b >= rem) { b -= rem; ++by; --rem; }
  const int bx = by + b;
  const int iBase = by * BM;   // output rows
  const int jBase = bx * BN;   // output cols

  __shared__ __align__(16) unsigned char As[3][4096];  // 4 frags x 1KB each
  __shared__ __align__(16) unsigned char Bs[3][4096];

  const int tid  = threadIdx.x;
  const int wave = tid >> 6, lane = tid & 63;
  const int wm = wave >> 1, wn = wave & 1;   // 2x2 wave grid, each wave 64x64
  const int r31 = lane & 31, khalf = lane >> 5;

  floatx16 acc[2][2];
  #pragma unroll
  for (int ai = 0; ai < 2; ++ai)
    #pragma unroll
    for (int ci = 0; ci < 2; ++ci)
      #pragma unroll
      for (int e = 0; e < 16; ++e) acc[ai][ci][e] = 0.f;

  // staging: wave w stages A-fragment w (rows iBase+w*32+r31) and B-fragment w.
  // per-lane source = the exact 16 B that lane consumes as an MFMA operand ->
  // LDS layout is lane-linear (wave-uniform base + lane*16).
  const unsigned char* srcA =
      P + (size_t)(iBase + wave * 32 + r31) * ROWB + khalf * 16;
  const unsigned char* srcB =
      P + (size_t)(jBase + wave * 32 + r31) * ROWB + khalf * 16;

  #define STAGE(buf, k0b)                                                     \
    {                                                                         \
      async_copy16(srcA + (k0b), &As[buf][wave * 1024]);                      \
      async_copy16(srcB + (k0b), &Bs[buf][wave * 1024]);                      \
    }

  STAGE(0, 0);          // prologue: depth-2 prefetch (4 vm-ops)
  STAGE(1, BKB);

  int cur = 0, pre = 2;
  for (int i = 0; i < NSTEP; ++i) {
    // stage(i) landed; stage(i+1)'s 2 loads stay in flight across the barrier
    asm volatile("s_waitcnt vmcnt(2)" ::: "memory");
    __builtin_amdgcn_s_barrier();

    // prefetch k-step i+2 (wraps harmlessly -> uniform waits)
    STAGE(pre, ((i + 2) * BKB) & (ROWB - 1));

    // fragment reads: lane-linear, conflict-free
    intx4 a4[2], b4[2];
    #pragma unroll
    for (int t = 0; t < 2; ++t) {
      a4[t] = *(const intx4*)&As[cur][(wm * 2 + t) * 1024 + lane * 16];
      b4[t] = *(const intx4*)&Bs[cur][(wn * 2 + t) * 1024 + lane * 16];
    }
    intx8 a8[2], b8[2];
    #pragma unroll
    for (int t = 0; t < 2; ++t) {
      #pragma unroll
      for (int e = 0; e < 4; ++e) {
        a8[t][e] = a4[t][e];  a8[t][e + 4] = 0;
        b8[t][e] = b4[t][e];  b8[t][e + 4] = 0;
      }
    }

    __builtin_amdgcn_s_setprio(1);
    #pragma unroll
    for (int tm = 0; tm < 2; ++tm)
      #pragma unroll
      for (int tn = 0; tn < 2; ++tn)
        acc[tm][tn] = __builtin_amdgcn_mfma_scale_f32_32x32x64_f8f6f4(
            a8[tm], b8[tn], acc[tm][tn],
            4, 4,            // cbsz/blgp: A,B format = fp4
            0, 127,          // scale_a opsel, e8m0 127 = 1.0
            0, 127);         // scale_b
    __builtin_amdgcn_s_setprio(0);

    cur = (cur == 2) ? 0 : cur + 1;
    pre = (pre == 2) ? 0 : pre + 1;
  }

  // epilogue: sim = -inter / (|A_i| + |A_j| - inter); write value + mirror.
  // 32x32 C layout: col = lane&31, row = (reg&3) + 8*(reg>>2) + 4*(lane>>5).
  #pragma unroll
  for (int tm = 0; tm < 2; ++tm) {
    const int rowb = iBase + wm * 64 + tm * 32 + 4 * khalf;
    #pragma unroll
    for (int tn = 0; tn < 2; ++tn) {
      const int colb = jBase + wn * 64 + tn * 32 + r31;
      const float sj = sizes[colb];
      #pragma unroll
      for (int q = 0; q < 4; ++q) {           // reg quads: rows rowb+8q..+3
        const int rq = rowb + 8 * q;
        floatx4 tv;
        #pragma unroll
        for (int j = 0; j < 4; ++j) {
          const float inter = acc[tm][tn][4 * q + j];
          const float u = sizes[rq + j] + sj - inter;
          tv[j] = (u != 0.f) ? (-inter / u) : 0.f;
        }
        // upper-triangle element (4 scalar rows at fixed col)
        __builtin_nontemporal_store(tv[0], &out[(size_t)(rq + 0) * B_ROWS + colb]);
        __builtin_nontemporal_store(tv[1], &out[(size_t)(rq + 1) * B_ROWS + colb]);
        __builtin_nontemporal_store(tv[2], &out[(size_t)(rq + 2) * B_ROWS + colb]);
        __builtin_nontemporal_store(tv[3], &out[(size_t)(rq + 3) * B_ROWS + colb]);
        // mirrored: 4 row-values contiguous in the transposed row (16B-aligned)
        __builtin_nontemporal_store(tv, (floatx4*)&out[(size_t)colb * B_ROWS + rq]);
      }
    }
  }
}

// ---------------- launcher ---------------------------------------------------
extern "C" void kernel_launch(void* const* d_in, const int* in_sizes, int n_in,
                              void* d_out, int out_size, void* d_ws, size_t ws_size,
                              hipStream_t stream) {
  const int* features = (const int*)d_in[0];
  float* out = (float*)d_out;
  uint32_t* P = (uint32_t*)d_ws;                                  // 16 MB fp4
  float* sizes = (float*)((char*)d_ws + (size_t)B_ROWS * ROWB);   // +16 KB

  presence_kernel<<<B_ROWS, 256, 0, stream>>>(features, P, sizes);
  gemm_kernel<<<528, 256, 0, stream>>>((const unsigned char*)P, sizes, out);
}

// Round 6
// 206.353 us; speedup vs baseline: 1.4526x; 1.2055x over previous
//
#include <hip/hip_runtime.h>
#include <stdint.h>

#define B_ROWS 4096
#define L_FEAT 256
#define VOCAB  8192
#define ROWB   (VOCAB / 2)      // 4096 bytes per row in fp4 (2 elems/byte)
#define BM 128
#define BN 128
#define BKE 128                 // K elements per step (2 MFMA-K)
#define BKB 64                  // K bytes per step per row
#define NSTEP (VOCAB / BKE)     // 64

typedef __attribute__((ext_vector_type(4)))  int   intx4;
typedef __attribute__((ext_vector_type(8)))  int   intx8;
typedef __attribute__((ext_vector_type(4)))  float floatx4;
typedef __attribute__((ext_vector_type(16))) float floatx16;

__device__ __forceinline__ void async_copy16(const void* gsrc, void* ldst) {
  __builtin_amdgcn_global_load_lds(
      (const __attribute__((address_space(1))) void*)gsrc,
      (__attribute__((address_space(3))) void*)ldst, 16, 0, 0);
}

// ---------------- kernel 1: fused zero+scatter+sizes (fp4, 4 rows/block) -----
// v2: 4 rows per block -> 3 __syncthreads per BLOCK (was 3 per row), 1024
// blocks. Phase 3: wave w owns row w (writes 4 KB coalesced + popcounts).
__global__ __launch_bounds__(256) void presence_kernel(
    const int* __restrict__ f,
    uint32_t* __restrict__ P,     // fp4 presence, ROWB bytes per row
    float* __restrict__ sizes) {
  __shared__ uint32_t rw[4][VOCAB / 8];   // 4 x 1024 words = 16 KB
  const int rbase = blockIdx.x * 4;
  const int tid = threadIdx.x;

  uint4* rp4 = (uint4*)&rw[0][0];         // 1024 uint4
  const uint4 z = make_uint4(0u, 0u, 0u, 0u);
  #pragma unroll
  for (int j = 0; j < 4; ++j) rp4[tid + j * 256] = z;
  __syncthreads();

  #pragma unroll
  for (int r = 0; r < 4; ++r) {
    const int v = f[(rbase + r) * L_FEAT + tid];     // coalesced
    atomicOr(&rw[r][v >> 3], 0x2u << ((v & 7) * 4)); // fp4 nibble 1.0; dups ok
  }
  __syncthreads();

  const int w = tid >> 6, lane = tid & 63;           // wave w owns row rbase+w
  uint4* op4 = (uint4*)(P + (size_t)(rbase + w) * (ROWB / 4));
  const uint4* sp4 = (const uint4*)&rw[w][0];        // 256 uint4
  int cnt = 0;
  #pragma unroll
  for (int q = 0; q < 4; ++q) {
    const uint4 x = sp4[lane + q * 64];
    op4[lane + q * 64] = x;
    cnt += __popc(x.x & 0x22222222u) + __popc(x.y & 0x22222222u) +
           __popc(x.z & 0x22222222u) + __popc(x.w & 0x22222222u);
  }
  #pragma unroll
  for (int off = 32; off > 0; off >>= 1) cnt += __shfl_down(cnt, off);
  if (lane == 0) sizes[rbase + w] = (float)cnt;
}

// ---------------- kernel 2: inter = P·P^T (fp4 MX MFMA) + Jaccard + mirror ---
// 128x128 tile, 4 waves 2x2 (wave = 64x64 = 2x2 of 32x32 frags), fp4 via
// mfma_scale_f32_32x32x64_f8f6f4 (unit e8m0 scales), K-step = 128 elems.
// Round-6 = round-3's PROVEN skeleton with fp4 payload:
//   * 3 buffers x 16 KB = 48 KB -> 3 blocks/CU; depth-2 prefetch; loop-top
//     counted vmcnt(4) (stage(i) landed, stage(i+1)'s 4 ops stay in flight
//     across the barrier -- never drains to 0); ONE s_barrier per K-step.
//   * per-step work: 8 MFMA/wave (~280 cyc) + 16 KB staging -- amortizes the
//     per-barrier fixed cost that sank round 5 (4 MFMA/step, 128 barriers).
//   * fragment-linear LDS chunks (1 KB per (frag,kk)): lane's 16 B staged at
//     base+lane*16 and read back at base+lane*16 -> conflict-free, no swizzle.
//   * XCD swizzle, setprio on MFMA, nt stores, fused mirror (all verified).
__global__ __launch_bounds__(256, 3) void gemm_kernel(
    const unsigned char* __restrict__ P,
    const float* __restrict__ sizes,
    float* __restrict__ out) {
  // XCD swizzle (528 = 8*66 -> bijective) then triangle decode, bx >= by
  int bid = blockIdx.x;
  bid = (bid & 7) * 66 + (bid >> 3);
  int b = bid, by = 0, rem = 32;
  while (b >= rem) { b -= rem; ++by; --rem; }
  const int bx = by + b;
  const int iBase = by * BM;   // output rows
  const int jBase = bx * BN;   // output cols

  // chunk(c) = (frag f = c>>1, kk = c&1): 1 KB, lane-linear
  __shared__ __align__(16) unsigned char As[3][8192];  // 8 chunks x 1 KB
  __shared__ __align__(16) unsigned char Bs[3][8192];

  const int tid  = threadIdx.x;
  const int wave = tid >> 6, lane = tid & 63;
  const int wm = wave >> 1, wn = wave & 1;   // 2x2 wave grid, each wave 64x64
  const int r31 = lane & 31, khalf = lane >> 5;

  floatx16 acc[2][2];
  #pragma unroll
  for (int ai = 0; ai < 2; ++ai)
    #pragma unroll
    for (int ci = 0; ci < 2; ++ci)
      #pragma unroll
      for (int e = 0; e < 16; ++e) acc[ai][ci][e] = 0.f;

  // staging: wave w copies chunks {w, w+4} of A and of B (4 ops/wave/step).
  // chunk c source for lane l: row (c>>1)*32 + (l&31), bytes
  // k0b + (c&1)*32 + (l>>5)*16; LDS dst = chunk_base (+ lane*16 implicit).
  const int c0 = wave, c1 = wave + 4;
  const unsigned char* srcA0 =
      P + (size_t)(iBase + (c0 >> 1) * 32 + r31) * ROWB + (c0 & 1) * 32 + khalf * 16;
  const unsigned char* srcA1 =
      P + (size_t)(iBase + (c1 >> 1) * 32 + r31) * ROWB + (c1 & 1) * 32 + khalf * 16;
  const unsigned char* srcB0 =
      P + (size_t)(jBase + (c0 >> 1) * 32 + r31) * ROWB + (c0 & 1) * 32 + khalf * 16;
  const unsigned char* srcB1 =
      P + (size_t)(jBase + (c1 >> 1) * 32 + r31) * ROWB + (c1 & 1) * 32 + khalf * 16;

  #define STAGE(buf, k0b)                                                     \
    {                                                                         \
      async_copy16(srcA0 + (k0b), &As[buf][c0 * 1024]);                       \
      async_copy16(srcA1 + (k0b), &As[buf][c1 * 1024]);                       \
      async_copy16(srcB0 + (k0b), &Bs[buf][c0 * 1024]);                       \
      async_copy16(srcB1 + (k0b), &Bs[buf][c1 * 1024]);                       \
    }

  STAGE(0, 0);          // prologue: depth-2 prefetch (8 vm-ops/wave)
  STAGE(1, BKB);

  int cur = 0, pre = 2;
  for (int i = 0; i < NSTEP; ++i) {
    // stage(i) landed; stage(i+1)'s 4 ops stay in flight across the barrier
    asm volatile("s_waitcnt vmcnt(4)" ::: "memory");
    __builtin_amdgcn_s_barrier();

    // prefetch k-step i+2 (wraps harmlessly -> uniform waits); writes buf
    // (i-1)%3 whose reads completed before barrier(i) -> race-free.
    STAGE(pre, ((i + 2) * BKB) & (ROWB - 1));

    // fragment reads: lane-linear ds_read_b128, conflict-free
    intx4 a4[2][2], b4[2][2];   // [tm|tn][kk]
    #pragma unroll
    for (int t = 0; t < 2; ++t)
      #pragma unroll
      for (int kk = 0; kk < 2; ++kk) {
        a4[t][kk] = *(const intx4*)
            &As[cur][((wm * 2 + t) * 2 + kk) * 1024 + lane * 16];
        b4[t][kk] = *(const intx4*)
            &Bs[cur][((wn * 2 + t) * 2 + kk) * 1024 + lane * 16];
      }

    __builtin_amdgcn_s_setprio(1);
    #pragma unroll
    for (int kk = 0; kk < 2; ++kk)
      #pragma unroll
      for (int tm = 0; tm < 2; ++tm)
        #pragma unroll
        for (int tn = 0; tn < 2; ++tn) {
          intx8 a8, b8;
          #pragma unroll
          for (int e = 0; e < 4; ++e) {
            a8[e] = a4[tm][kk][e];  a8[e + 4] = 0;
            b8[e] = b4[tn][kk][e];  b8[e + 4] = 0;
          }
          acc[tm][tn] = __builtin_amdgcn_mfma_scale_f32_32x32x64_f8f6f4(
              a8, b8, acc[tm][tn],
              4, 4,            // cbsz/blgp: A,B format = fp4
              0, 127,          // scale_a opsel, e8m0 127 = 1.0
              0, 127);         // scale_b
        }
    __builtin_amdgcn_s_setprio(0);

    cur = (cur == 2) ? 0 : cur + 1;
    pre = (pre == 2) ? 0 : pre + 1;
  }

  // epilogue (verified round 5): sim = -inter/(|A_i|+|A_j|-inter), + mirror.
  // 32x32 C layout: col = lane&31, row = (reg&3) + 8*(reg>>2) + 4*(lane>>5).
  #pragma unroll
  for (int tm = 0; tm < 2; ++tm) {
    const int rowb = iBase + wm * 64 + tm * 32 + 4 * khalf;
    #pragma unroll
    for (int tn = 0; tn < 2; ++tn) {
      const int colb = jBase + wn * 64 + tn * 32 + r31;
      const float sj = sizes[colb];
      #pragma unroll
      for (int q = 0; q < 4; ++q) {           // reg quads: rows rq..rq+3
        const int rq = rowb + 8 * q;
        floatx4 tv;
        #pragma unroll
        for (int j = 0; j < 4; ++j) {
          const float inter = acc[tm][tn][4 * q + j];
          const float u = sizes[rq + j] + sj - inter;
          tv[j] = (u != 0.f) ? (-inter / u) : 0.f;
        }
        __builtin_nontemporal_store(tv[0], &out[(size_t)(rq + 0) * B_ROWS + colb]);
        __builtin_nontemporal_store(tv[1], &out[(size_t)(rq + 1) * B_ROWS + colb]);
        __builtin_nontemporal_store(tv[2], &out[(size_t)(rq + 2) * B_ROWS + colb]);
        __builtin_nontemporal_store(tv[3], &out[(size_t)(rq + 3) * B_ROWS + colb]);
        // mirrored: 4 row-values contiguous in the transposed row (16B-aligned)
        __builtin_nontemporal_store(tv, (floatx4*)&out[(size_t)colb * B_ROWS + rq]);
      }
    }
  }
}

// ---------------- launcher ---------------------------------------------------
extern "C" void kernel_launch(void* const* d_in, const int* in_sizes, int n_in,
                              void* d_out, int out_size, void* d_ws, size_t ws_size,
                              hipStream_t stream) {
  const int* features = (const int*)d_in[0];
  float* out = (float*)d_out;
  uint32_t* P = (uint32_t*)d_ws;                                  // 16 MB fp4
  float* sizes = (float*)((char*)d_ws + (size_t)B_ROWS * ROWB);   // +16 KB

  presence_kernel<<<B_ROWS / 4, 256, 0, stream>>>(features, P, sizes);
  gemm_kernel<<<528, 256, 0, stream>>>((const unsigned char*)P, sizes, out);
}